// Round 5
// baseline (88.163 us; speedup 1.0000x reference)
//
#include <hip/hip_runtime.h>

// PositionAwareARCEncoder fused kernels.
// B=32768, H=W=5, NC=4, E=64, HID=128, OUT=128, NH=4, HD=16.
//
// Tables in d_ws (~345 KB):
//  ktab/vtab[c][ij][64], outproj[c][ij][128] (1/25 folded)
//  qtab[p][64], cpeproj[p][128] (p=25 -> cpe=0)
//  wov[64][128] = o_w @ cb_w1[0:64];  bias1 = cb_b1 + o_b @ cb_w1[0:64]
//  stab[cpe][ig][ij][h] = per-head q.k * HD^-0.5
//  wovT/cbw2T bf16 transposed (MFMA B-frags, read direct from global)
//  outproj2[pair 12][og4 16][128] = outproj[c0,2p] + outproj[c1,2p+1]
//
// prepA: per-cij MLPs + ktab/vtab/outproj + small tables  (110 blocks)
// prepB: stab + bf16 weight transposes + outproj2         (233 blocks)
// arc_fused: block = 16 batches = 4 waves; phase A (decode/softmax/ra/pre in
//   LDS) -> phase B (MFMA dense layers, hi/lo bf16 compensated).
//   No cb_w2 LDS staging -> 20.7 KB LDS -> 7 blocks/CU occupancy.

typedef __attribute__((ext_vector_type(8))) short short8v;
typedef __attribute__((ext_vector_type(4))) float float4v;

static __device__ __forceinline__ unsigned short f2bf(float f) {
  unsigned int u = __float_as_uint(f);
  unsigned int r = (u + 0x7fffu + ((u >> 16) & 1u)) >> 16;
  return (unsigned short)r;
}
static __device__ __forceinline__ float bf2f(unsigned short s) {
  return __uint_as_float(((unsigned int)s) << 16);
}
// spread 25 bits into even positions of 50 bits (Morton)
static __device__ __forceinline__ unsigned long long spread25(unsigned long long x) {
  x &= 0x1FFFFFFull;
  x = (x | (x << 16)) & 0x0000FFFF0000FFFFull;
  x = (x | (x << 8))  & 0x00FF00FF00FF00FFull;
  x = (x | (x << 4))  & 0x0F0F0F0F0F0F0F0Full;
  x = (x | (x << 2))  & 0x3333333333333333ull;
  x = (x | (x << 1))  & 0x5555555555555555ull;
  return x;
}

__global__ __launch_bounds__(128) void prepA(
    const float* __restrict__ color_embed, const float* __restrict__ row_embed,
    const float* __restrict__ col_embed,
    const float* __restrict__ ip_w1, const float* __restrict__ ip_b1,
    const float* __restrict__ ip_w2, const float* __restrict__ ip_b2,
    const float* __restrict__ op_w1, const float* __restrict__ op_b1,
    const float* __restrict__ op_w2, const float* __restrict__ op_b2,
    const float* __restrict__ k_w, const float* __restrict__ k_b,
    const float* __restrict__ v_w, const float* __restrict__ v_b,
    const float* __restrict__ q_w, const float* __restrict__ q_b,
    const float* __restrict__ o_w, const float* __restrict__ o_b,
    const float* __restrict__ cb_w1, const float* __restrict__ cb_b1,
    float* __restrict__ ktab, float* __restrict__ vtab,
    float* __restrict__ outproj, float* __restrict__ qtab,
    float* __restrict__ cpeproj, float* __restrict__ wov,
    float* __restrict__ bias1) {
  const int bid = blockIdx.x, t = threadIdx.x;
  if (bid < 100) {
    __shared__ float feat[128], h1[128], val[64];
    const int c = bid / 25, ij = bid % 25, gi = ij / 5, gj = ij % 5;
    if (t < 64)      feat[t] = color_embed[c * 64 + t];
    else if (t < 96) feat[t] = row_embed[gi * 32 + (t - 64)];
    else             feat[t] = col_embed[gj * 32 + (t - 96)];
    __syncthreads();
    // input MLP
    float a = ip_b1[t];
#pragma unroll 8
    for (int d = 0; d < 128; ++d) a = fmaf(feat[d], ip_w1[d * 128 + t], a);
    h1[t] = fmaxf(a, 0.f);
    __syncthreads();
    if (t < 64) {
      float v = ip_b2[t];
#pragma unroll 8
      for (int d = 0; d < 128; ++d) v = fmaf(h1[d], ip_w2[d * 64 + t], v);
      val[t] = v;
    }
    __syncthreads();
    {  // k / v projections of inpval
      const int e2 = t & 63;
      const float* w = (t < 64) ? k_w : v_w;
      float a2 = (t < 64) ? k_b[e2] : v_b[e2];
#pragma unroll 8
      for (int e = 0; e < 64; ++e) a2 = fmaf(val[e], w[e * 64 + e2], a2);
      ((t < 64) ? ktab : vtab)[bid * 64 + e2] = a2;
    }
    __syncthreads();
    // output MLP
    float b = op_b1[t];
#pragma unroll 8
    for (int d = 0; d < 128; ++d) b = fmaf(feat[d], op_w1[d * 128 + t], b);
    h1[t] = fmaxf(b, 0.f);
    __syncthreads();
    if (t < 64) {
      float v = op_b2[t];
#pragma unroll 8
      for (int d = 0; d < 128; ++d) v = fmaf(h1[d], op_w2[d * 64 + t], v);
      val[t] = v;
    }
    __syncthreads();
    float o = 0.f;
#pragma unroll 8
    for (int e = 0; e < 64; ++e) o = fmaf(val[e], cb_w1[(64 + e) * 128 + t], o);
    outproj[bid * 128 + t] = o * (1.f / 25.f);
  } else if (bid == 100) {
    for (int i = t; i < 1664; i += 128) {   // qtab[26][64]
      const int p = i >> 6, e2 = i & 63;
      float a = q_b[e2];
      if (p < 25) {
        const int r = p / 5, cc = p % 5;
#pragma unroll 8
        for (int e = 0; e < 32; ++e) a = fmaf(row_embed[r * 32 + e], q_w[e * 64 + e2], a);
#pragma unroll 8
        for (int e = 0; e < 32; ++e) a = fmaf(col_embed[cc * 32 + e], q_w[(32 + e) * 64 + e2], a);
      }
      qtab[i] = a;
    }
    float a = cb_b1[t];
#pragma unroll 8
    for (int e = 0; e < 64; ++e) a = fmaf(o_b[e], cb_w1[e * 128 + t], a);
    bias1[t] = a;
  } else if (bid == 101) {
    for (int i = t; i < 3328; i += 128) {   // cpeproj[26][128]
      const int p = i >> 7, jj = i & 127;
      float a = 0.f;
      if (p < 25) {
        const int r = p / 5, cc = p % 5;
#pragma unroll 8
        for (int e = 0; e < 32; ++e) a = fmaf(row_embed[r * 32 + e], cb_w1[(128 + e) * 128 + jj], a);
#pragma unroll 8
        for (int e = 0; e < 32; ++e) a = fmaf(col_embed[cc * 32 + e], cb_w1[(160 + e) * 128 + jj], a);
      }
      cpeproj[i] = a;
    }
  } else {                                   // bid 102..109: wov[64][128]
    const int base = (bid - 102) * 1024;
    for (int i = t; i < 1024; i += 128) {
      const int idx = base + i, d = idx >> 7, jj = idx & 127;
      float a = 0.f;
#pragma unroll 8
      for (int e = 0; e < 64; ++e) a = fmaf(o_w[d * 64 + e], cb_w1[e * 128 + jj], a);
      wov[idx] = a;
    }
  }
}

__global__ void prepB(const float* __restrict__ qtab, const float* __restrict__ ktab,
                      const float* __restrict__ wov, const float* __restrict__ cb_w2,
                      const float* __restrict__ outproj,
                      float* __restrict__ stab, unsigned short* __restrict__ wovT,
                      unsigned short* __restrict__ cbw2T, float* __restrict__ outproj2) {
  const int tid = blockIdx.x * 256 + threadIdx.x;
  if (tid < 10400) {                         // stab[cpe][ig][ij][h]
    const int h = tid & 3;
    const int ij = (tid >> 2) % 25;
    const int ig = ((tid >> 2) / 25) & 3;
    const int cpe = (tid >> 2) / 100;
    const float* qq = qtab + cpe * 64 + h * 16;
    const float* kk = ktab + (ig * 25 + ij) * 64 + h * 16;
    float a = 0.f;
#pragma unroll
    for (int d = 0; d < 16; ++d) a = fmaf(qq[d], kk[d], a);
    stab[tid] = a * 0.25f;
  } else if (tid < 18592) {                  // wovT[col 128][k 64]
    const int i = tid - 10400;
    const int j = i >> 6, d = i & 63;
    wovT[i] = f2bf(wov[d * 128 + j]);
  } else if (tid < 34976) {                  // cbw2T[col 128][k 128]
    const int i = tid - 18592;
    const int j = i >> 7, k = i & 127;
    cbw2T[i] = f2bf(cb_w2[k * 128 + j]);
  } else if (tid < 59552) {                  // outproj2[pair 12][og4 16][128]
    const int i = tid - 34976;
    const int j = i & 127, pm = i >> 7, m = pm & 15, p = pm >> 4;
    const int c0 = m & 3, c1 = (m >> 2) & 3;
    outproj2[i] = outproj[(c0 * 25 + 2 * p) * 128 + j] +
                  outproj[(c1 * 25 + 2 * p + 1) * 128 + j];
  }
}

__global__ __launch_bounds__(256) void arc_fused(
    const int* __restrict__ obs,
    const float* __restrict__ stab, const float* __restrict__ vtab,
    const float* __restrict__ outproj, const float* __restrict__ outproj2,
    const float* __restrict__ cpeproj, const float* __restrict__ bias1,
    const unsigned short* __restrict__ wovT, const unsigned short* __restrict__ cbw2T,
    const float* __restrict__ cb_b2, float* __restrict__ out) {
  __shared__ float lds_pre[16][132];  // pre-activation fp32, +4 pad
  __shared__ short lds_raH[1024];     // ra hi bf16 [16][64], swizzled
  __shared__ short lds_raL[1024];     // ra lo
  __shared__ short lds_hidH[2048];    // hidden hi bf16 [16][128], swizzled
  __shared__ short lds_hidL[2048];    // hidden lo
  // total 20.7 KB -> 7 blocks/CU

  const int tid = threadIdx.x;
  const int lane = tid & 63, wv = tid >> 6;
  const int row16 = lane & 15, g4 = lane >> 4;
  const int bbase = blockIdx.x * 16;

  // ---------------- phase A: 4 batches per wave ----------------
#pragma unroll 2
  for (int e = 0; e < 4; ++e) {
    const int r = wv * 4 + e;              // local row 0..15
    const int b = bbase + r;
    const int* ob = obs + b * 75;
    const int x = ob[lane];
    const int y = (lane < 11) ? ob[64 + lane] : 0;
    const unsigned long long ig_lo = __ballot((lane < 25) && (x & 1));
    const unsigned long long ig_hi = __ballot((lane < 25) && (x & 2));
    const unsigned long long og_lo = __ballot((lane >= 25) && (lane < 50) && (x & 1)) >> 25;
    const unsigned long long og_hi = __ballot((lane >= 25) && (lane < 50) && (x & 2)) >> 25;
    const unsigned long long mb =
        (__ballot((lane >= 50) && (x != 0)) >> 50) |
        (__ballot((lane < 11) && (y != 0)) << 14);
    const int cpe_idx = mb ? __builtin_ctzll((long long)mb) : 25;
    const unsigned long long og2 = spread25(og_lo) | (spread25(og_hi) << 1);

    // scores: wave-uniform float4 loads, select head component (head = g4)
    const int sb = __builtin_amdgcn_readfirstlane(cpe_idx * 400);
    float sc[25];
    float mx = -1e30f;
#pragma unroll
    for (int ij = 0; ij < 25; ++ij) {
      const int ig = (int)((ig_lo >> ij) & 1ull) | ((int)((ig_hi >> ij) & 1ull) << 1);
      const float4 s4 = *(const float4*)(stab + sb + ig * 100 + ij * 4);
      const float sv = (g4 < 2) ? (g4 == 0 ? s4.x : s4.y) : (g4 == 2 ? s4.z : s4.w);
      sc[ij] = sv;
      mx = fmaxf(mx, sv);
    }
    float s = 0.f;
#pragma unroll
    for (int ij = 0; ij < 25; ++ij) { sc[ij] = __expf(sc[ij] - mx); s += sc[ij]; }
    const float inv = 1.0f / s;

    float ra = 0.f;
#pragma unroll
    for (int ij = 0; ij < 25; ++ij) {
      const int ig = (int)((ig_lo >> ij) & 1ull) | ((int)((ig_hi >> ij) & 1ull) << 1);
      ra = fmaf(sc[ij], vtab[(ig * 25 + ij) * 64 + lane], ra);
    }
    ra *= inv;
    const unsigned short hi = f2bf(ra);
    const int raoff = (r * 128 + lane * 2) ^ ((r & 7) << 4);
    *(short*)((char*)lds_raH + raoff) = (short)hi;
    *(short*)((char*)lds_raL + raoff) = (short)f2bf(ra - bf2f(hi));

    // pre = bias1 + cpeproj[cpe] + pair-table sums + cell24; lane -> cols 2l,2l+1
    float2 a2 = ((const float2*)bias1)[lane];
    const float2 cp = ((const float2*)cpeproj)[cpe_idx * 64 + lane];
    a2.x += cp.x; a2.y += cp.y;
#pragma unroll
    for (int p = 0; p < 12; ++p) {
      const int og4 = (int)((og2 >> (4 * p)) & 15ull);
      const float2 v = ((const float2*)outproj2)[(p * 16 + og4) * 64 + lane];
      a2.x += v.x; a2.y += v.y;
    }
    {
      const int og24 = (int)((og2 >> 48) & 3ull);
      const float2 v = ((const float2*)outproj)[(og24 * 25 + 24) * 64 + lane];
      a2.x += v.x; a2.y += v.y;
    }
    *(float2*)&lds_pre[r][2 * lane] = a2;
  }
  __syncthreads();

  // ---------------- phase B: MFMA dense layers ----------------
  // Wave wv owns column-tiles nt = wv*2, wv*2+1. B-frags direct from global.
  const int rswz = (row16 & 7) << 4;
  const short8v aH0 = *(const short8v*)((char*)lds_raH + ((row16 * 128 + g4 * 16) ^ rswz));
  const short8v aH1 = *(const short8v*)((char*)lds_raH + ((row16 * 128 + 64 + g4 * 16) ^ rswz));
  const short8v aL0 = *(const short8v*)((char*)lds_raL + ((row16 * 128 + g4 * 16) ^ rswz));
  const short8v aL1 = *(const short8v*)((char*)lds_raL + ((row16 * 128 + 64 + g4 * 16) ^ rswz));

  float4v acc[2];
  short8v bw[2][2];
#pragma unroll
  for (int t = 0; t < 2; ++t) {
    const int nt = wv * 2 + t;
#pragma unroll
    for (int ks = 0; ks < 2; ++ks)
      bw[t][ks] = *(const short8v*)(wovT + (nt * 16 + row16) * 64 + ks * 32 + g4 * 8);
    // C-init from pre (C/D layout: col = lane&15, row = (lane>>4)*4 + reg)
#pragma unroll
    for (int rr = 0; rr < 4; ++rr)
      acc[t][rr] = lds_pre[g4 * 4 + rr][nt * 16 + row16];
  }
#pragma unroll
  for (int t = 0; t < 2; ++t) {
    acc[t] = __builtin_amdgcn_mfma_f32_16x16x32_bf16(aL0, bw[t][0], acc[t], 0, 0, 0);
    acc[t] = __builtin_amdgcn_mfma_f32_16x16x32_bf16(aL1, bw[t][1], acc[t], 0, 0, 0);
    acc[t] = __builtin_amdgcn_mfma_f32_16x16x32_bf16(aH0, bw[t][0], acc[t], 0, 0, 0);
    acc[t] = __builtin_amdgcn_mfma_f32_16x16x32_bf16(aH1, bw[t][1], acc[t], 0, 0, 0);
  }

  // relu -> hidden bf16 hi+lo into swizzled LDS
#pragma unroll
  for (int t = 0; t < 2; ++t) {
    const int col = (wv * 2 + t) * 16 + row16;
#pragma unroll
    for (int rr = 0; rr < 4; ++rr) {
      const int row = g4 * 4 + rr;
      const float hv = fmaxf(acc[t][rr], 0.f);
      const unsigned short hb = f2bf(hv);
      const int off = (row * 256 + col * 2) ^ ((row & 7) << 4);
      *(short*)((char*)lds_hidH + off) = (short)hb;
      *(short*)((char*)lds_hidL + off) = (short)f2bf(hv - bf2f(hb));
    }
  }
  __syncthreads();

  // out = hidden @ cb_w2 + b2 (B-frags direct from cbw2T global, L1-hot)
  short8v ahH[4], ahL[4];
#pragma unroll
  for (int ks = 0; ks < 4; ++ks) {
    const int off = (row16 * 256 + ks * 64 + g4 * 16) ^ rswz;
    ahH[ks] = *(const short8v*)((char*)lds_hidH + off);
    ahL[ks] = *(const short8v*)((char*)lds_hidL + off);
  }
#pragma unroll
  for (int t = 0; t < 2; ++t) {
    const int col = (wv * 2 + t) * 16 + row16;
    float4v c2 = {0.f, 0.f, 0.f, 0.f};
#pragma unroll
    for (int ks = 0; ks < 4; ++ks) {
      const short8v bb = *(const short8v*)(cbw2T + col * 128 + ks * 32 + g4 * 8);
      c2 = __builtin_amdgcn_mfma_f32_16x16x32_bf16(ahL[ks], bb, c2, 0, 0, 0);
      c2 = __builtin_amdgcn_mfma_f32_16x16x32_bf16(ahH[ks], bb, c2, 0, 0, 0);
    }
    const float bv = cb_b2[col];
#pragma unroll
    for (int rr = 0; rr < 4; ++rr)
      out[(bbase + g4 * 4 + rr) * 128 + col] = c2[rr] + bv;
  }
}

extern "C" void kernel_launch(void* const* d_in, const int* in_sizes, int n_in,
                              void* d_out, int out_size, void* d_ws, size_t ws_size,
                              hipStream_t stream) {
  const int*   obs         = (const int*)d_in[0];
  const float* color_embed = (const float*)d_in[1];
  const float* row_embed   = (const float*)d_in[2];
  const float* col_embed   = (const float*)d_in[3];
  const float* ip_w1 = (const float*)d_in[4];
  const float* ip_b1 = (const float*)d_in[5];
  const float* ip_w2 = (const float*)d_in[6];
  const float* ip_b2 = (const float*)d_in[7];
  const float* q_w = (const float*)d_in[8];
  const float* q_b = (const float*)d_in[9];
  const float* k_w = (const float*)d_in[10];
  const float* k_b = (const float*)d_in[11];
  const float* v_w = (const float*)d_in[12];
  const float* v_b = (const float*)d_in[13];
  const float* o_w = (const float*)d_in[14];
  const float* o_b = (const float*)d_in[15];
  const float* op_w1 = (const float*)d_in[16];
  const float* op_b1 = (const float*)d_in[17];
  const float* op_w2 = (const float*)d_in[18];
  const float* op_b2 = (const float*)d_in[19];
  const float* cb_w1 = (const float*)d_in[20];
  const float* cb_b1 = (const float*)d_in[21];
  const float* cb_w2 = (const float*)d_in[22];
  const float* cb_b2 = (const float*)d_in[23];

  float* ws = (float*)d_ws;
  float* qtab    = ws;                 // 1664
  float* cpeproj = qtab + 1664;        // 3328
  float* ktab    = cpeproj + 3328;     // 6400
  float* vtab    = ktab + 6400;        // 6400
  float* outproj = vtab + 6400;        // 12800
  float* wov     = outproj + 12800;    // 8192
  float* bias1   = wov + 8192;         // 128
  float* stab    = bias1 + 128;        // 10400
  unsigned short* wovT  = (unsigned short*)(stab + 10400);   // 8192 shorts (4096 f)
  unsigned short* cbw2T = (unsigned short*)((float*)d_ws + 53408); // 16384 shorts (8192 f)
  float* outproj2 = (float*)d_ws + 61600;  // 24576
  // total 86176 floats ≈ 345 KB of d_ws

  prepA<<<110, 128, 0, stream>>>(color_embed, row_embed, col_embed,
                                 ip_w1, ip_b1, ip_w2, ip_b2,
                                 op_w1, op_b1, op_w2, op_b2,
                                 k_w, k_b, v_w, v_b, q_w, q_b, o_w, o_b,
                                 cb_w1, cb_b1,
                                 ktab, vtab, outproj, qtab, cpeproj, wov, bias1);
  prepB<<<233, 256, 0, stream>>>(qtab, ktab, wov, cb_w2, outproj,
                                 stab, wovT, cbw2T, outproj2);
  arc_fused<<<2048, 256, 0, stream>>>(obs, stab, vtab, outproj, outproj2,
                                      cpeproj, bias1, wovT, cbw2T, cb_b2,
                                      (float*)d_out);
}

// Round 6
// 69.506 us; speedup vs baseline: 1.2684x; 1.2684x over previous
//
#include <hip/hip_runtime.h>

// PositionAwareARCEncoder fused kernels.
// B=32768, H=W=5, NC=4, E=64, HID=128, OUT=128, NH=4, HD=16.
//
// Tables in d_ws (~345 KB):
//  ktab/vtab[c][ij][64], outproj[c][ij][128] (1/25 folded)
//  qtab[p][64], cpeproj[p][128] (p=25 -> cpe=0)
//  wov[64][128] = o_w @ cb_w1[0:64];  bias1 = cb_b1 + o_b @ cb_w1[0:64]
//  stab[cpe][ig][ij][h] = per-head q.k * HD^-0.5
//  wovT/cbw2T bf16 transposed (MFMA B-frags, read direct from global)
//  outproj2[pair 12][og4 16][128] = outproj[c0,2p] + outproj[c1,2p+1]
//
// prep12/prep3/prepC: flat parallel table builds (R3 shape — R4's merged
//   serial prepA cost ~32 µs vs ~11 µs for this shape).
// arc_fused: block = 16 batches = 4 waves; phase A (decode/softmax/ra/pre in
//   LDS, 4-way partial trees to cut dep chains) -> phase B (MFMA dense
//   layers, hi/lo bf16 compensated). 20.7 KB LDS -> 7 blocks/CU.

typedef __attribute__((ext_vector_type(8))) short short8v;
typedef __attribute__((ext_vector_type(4))) float float4v;

static __device__ __forceinline__ unsigned short f2bf(float f) {
  unsigned int u = __float_as_uint(f);
  unsigned int r = (u + 0x7fffu + ((u >> 16) & 1u)) >> 16;
  return (unsigned short)r;
}
static __device__ __forceinline__ float bf2f(unsigned short s) {
  return __uint_as_float(((unsigned int)s) << 16);
}
// spread 25 bits into even positions of 50 bits (Morton)
static __device__ __forceinline__ unsigned long long spread25(unsigned long long x) {
  x &= 0x1FFFFFFull;
  x = (x | (x << 16)) & 0x0000FFFF0000FFFFull;
  x = (x | (x << 8))  & 0x00FF00FF00FF00FFull;
  x = (x | (x << 4))  & 0x0F0F0F0F0F0F0F0Full;
  x = (x | (x << 2))  & 0x3333333333333333ull;
  x = (x | (x << 1))  & 0x5555555555555555ull;
  return x;
}

__global__ void prep12(const float* __restrict__ color_embed,
                       const float* __restrict__ row_embed,
                       const float* __restrict__ col_embed,
                       const float* __restrict__ ip_w1, const float* __restrict__ ip_b1,
                       const float* __restrict__ ip_w2, const float* __restrict__ ip_b2,
                       const float* __restrict__ op_w1, const float* __restrict__ op_b1,
                       const float* __restrict__ op_w2, const float* __restrict__ op_b2,
                       float* __restrict__ inpval, float* __restrict__ outval) {
  __shared__ float feat[128];
  __shared__ float h1[128];
  const int bid = blockIdx.x;       // 0..199
  const int path = bid / 100;
  const int cij = bid % 100;
  const int c = cij / 25, ij = cij % 25, gi = ij / 5, gj = ij % 5;
  const int t = threadIdx.x;        // 128 threads
  if (t < 64)      feat[t] = color_embed[c * 64 + t];
  else if (t < 96) feat[t] = row_embed[gi * 32 + (t - 64)];
  else             feat[t] = col_embed[gj * 32 + (t - 96)];
  __syncthreads();
  const float* w1 = path ? op_w1 : ip_w1;
  const float* b1 = path ? op_b1 : ip_b1;
  float acc = b1[t];
#pragma unroll 8
  for (int d = 0; d < 128; ++d) acc = fmaf(feat[d], w1[d * 128 + t], acc);
  h1[t] = fmaxf(acc, 0.f);
  __syncthreads();
  if (t < 64) {
    const float* w2 = path ? op_w2 : ip_w2;
    const float* b2 = path ? op_b2 : ip_b2;
    float v = b2[t];
#pragma unroll 8
    for (int d = 0; d < 128; ++d) v = fmaf(h1[d], w2[d * 64 + t], v);
    (path ? outval : inpval)[cij * 64 + t] = v;
  }
}

__global__ void prep3(const float* __restrict__ row_embed, const float* __restrict__ col_embed,
                      const float* __restrict__ k_w, const float* __restrict__ k_b,
                      const float* __restrict__ v_w, const float* __restrict__ v_b,
                      const float* __restrict__ q_w, const float* __restrict__ q_b,
                      const float* __restrict__ o_w, const float* __restrict__ o_b,
                      const float* __restrict__ cb_w1, const float* __restrict__ cb_b1,
                      const float* __restrict__ inpval, const float* __restrict__ outval,
                      float* __restrict__ ktab, float* __restrict__ vtab,
                      float* __restrict__ outproj, float* __restrict__ qtab,
                      float* __restrict__ cpeproj, float* __restrict__ wov,
                      float* __restrict__ bias1) {
  const int tid = blockIdx.x * 256 + threadIdx.x;
  if (tid < 6400) {                       // ktab[100][64]
    const int cij = tid >> 6, e2 = tid & 63;
    const float* x = inpval + cij * 64;
    float a = k_b[e2];
#pragma unroll 8
    for (int e = 0; e < 64; ++e) a = fmaf(x[e], k_w[e * 64 + e2], a);
    ktab[tid] = a;
  } else if (tid < 12800) {               // vtab[100][64]
    const int l = tid - 6400;
    const int cij = l >> 6, e2 = l & 63;
    const float* x = inpval + cij * 64;
    float a = v_b[e2];
#pragma unroll 8
    for (int e = 0; e < 64; ++e) a = fmaf(x[e], v_w[e * 64 + e2], a);
    vtab[l] = a;
  } else if (tid < 25600) {               // outproj[100][128] (1/25 folded)
    const int l = tid - 12800;
    const int cij = l >> 7, jj = l & 127;
    const float* x = outval + cij * 64;
    float a = 0.f;
#pragma unroll 8
    for (int e = 0; e < 64; ++e) a = fmaf(x[e], cb_w1[(64 + e) * 128 + jj], a);
    outproj[l] = a * (1.f / 25.f);
  } else if (tid < 27264) {               // qtab[26][64]
    const int l = tid - 25600;
    const int p = l >> 6, e2 = l & 63;
    float a = q_b[e2];
    if (p < 25) {
      const int r = p / 5, c = p % 5;
#pragma unroll 8
      for (int e = 0; e < 32; ++e) a = fmaf(row_embed[r * 32 + e], q_w[e * 64 + e2], a);
#pragma unroll 8
      for (int e = 0; e < 32; ++e) a = fmaf(col_embed[c * 32 + e], q_w[(32 + e) * 64 + e2], a);
    }
    qtab[l] = a;
  } else if (tid < 30592) {               // cpeproj[26][128]
    const int l = tid - 27264;
    const int p = l >> 7, jj = l & 127;
    float a = 0.f;
    if (p < 25) {
      const int r = p / 5, c = p % 5;
#pragma unroll 8
      for (int e = 0; e < 32; ++e) a = fmaf(row_embed[r * 32 + e], cb_w1[(128 + e) * 128 + jj], a);
#pragma unroll 8
      for (int e = 0; e < 32; ++e) a = fmaf(col_embed[c * 32 + e], cb_w1[(160 + e) * 128 + jj], a);
    }
    cpeproj[l] = a;
  } else if (tid < 38784) {               // wov[64][128]
    const int l = tid - 30592;
    const int d = l >> 7, jj = l & 127;
    float a = 0.f;
#pragma unroll 8
    for (int e = 0; e < 64; ++e) a = fmaf(o_w[d * 64 + e], cb_w1[e * 128 + jj], a);
    wov[l] = a;
  } else if (tid < 38912) {               // bias1[128]
    const int jj = tid - 38784;
    float a = cb_b1[jj];
#pragma unroll 8
    for (int e = 0; e < 64; ++e) a = fmaf(o_b[e], cb_w1[e * 128 + jj], a);
    bias1[jj] = a;
  }
}

// stab + bf16 transposes + outproj2 (after prep3)
__global__ void prepC(const float* __restrict__ qtab, const float* __restrict__ ktab,
                      const float* __restrict__ wov, const float* __restrict__ cb_w2,
                      const float* __restrict__ outproj,
                      float* __restrict__ stab, unsigned short* __restrict__ wovT,
                      unsigned short* __restrict__ cbw2T, float* __restrict__ outproj2) {
  const int tid = blockIdx.x * 256 + threadIdx.x;
  if (tid < 10400) {                         // stab[cpe][ig][ij][h]
    const int h = tid & 3;
    const int ij = (tid >> 2) % 25;
    const int ig = ((tid >> 2) / 25) & 3;
    const int cpe = (tid >> 2) / 100;
    const float* qq = qtab + cpe * 64 + h * 16;
    const float* kk = ktab + (ig * 25 + ij) * 64 + h * 16;
    float a = 0.f;
#pragma unroll
    for (int d = 0; d < 16; ++d) a = fmaf(qq[d], kk[d], a);
    stab[tid] = a * 0.25f;
  } else if (tid < 18592) {                  // wovT[col 128][k 64]
    const int i = tid - 10400;
    const int j = i >> 6, d = i & 63;
    wovT[i] = f2bf(wov[d * 128 + j]);
  } else if (tid < 34976) {                  // cbw2T[col 128][k 128]
    const int i = tid - 18592;
    const int j = i >> 7, k = i & 127;
    cbw2T[i] = f2bf(cb_w2[k * 128 + j]);
  } else if (tid < 59552) {                  // outproj2[pair 12][og4 16][128]
    const int i = tid - 34976;
    const int j = i & 127, pm = i >> 7, m = pm & 15, p = pm >> 4;
    const int c0 = m & 3, c1 = (m >> 2) & 3;
    outproj2[i] = outproj[(c0 * 25 + 2 * p) * 128 + j] +
                  outproj[(c1 * 25 + 2 * p + 1) * 128 + j];
  }
}

__global__ __launch_bounds__(256) void arc_fused(
    const int* __restrict__ obs,
    const float* __restrict__ stab, const float* __restrict__ vtab,
    const float* __restrict__ outproj, const float* __restrict__ outproj2,
    const float* __restrict__ cpeproj, const float* __restrict__ bias1,
    const unsigned short* __restrict__ wovT, const unsigned short* __restrict__ cbw2T,
    const float* __restrict__ cb_b2, float* __restrict__ out) {
  __shared__ float lds_pre[16][132];  // pre-activation fp32, +4 pad
  __shared__ short lds_raH[1024];     // ra hi bf16 [16][64], swizzled
  __shared__ short lds_raL[1024];     // ra lo
  __shared__ short lds_hidH[2048];    // hidden hi bf16 [16][128], swizzled
  __shared__ short lds_hidL[2048];    // hidden lo
  // total 20.7 KB -> 7 blocks/CU

  const int tid = threadIdx.x;
  const int lane = tid & 63, wv = tid >> 6;
  const int row16 = lane & 15, g4 = lane >> 4;
  const int bbase = blockIdx.x * 16;

  // ---------------- phase A: 4 batches per wave ----------------
#pragma unroll 2
  for (int e = 0; e < 4; ++e) {
    const int r = wv * 4 + e;              // local row 0..15
    const int b = bbase + r;
    const int* ob = obs + b * 75;
    const int x = ob[lane];
    const int y = (lane < 11) ? ob[64 + lane] : 0;
    const unsigned long long ig_lo = __ballot((lane < 25) && (x & 1));
    const unsigned long long ig_hi = __ballot((lane < 25) && (x & 2));
    const unsigned long long og_lo = __ballot((lane >= 25) && (lane < 50) && (x & 1)) >> 25;
    const unsigned long long og_hi = __ballot((lane >= 25) && (lane < 50) && (x & 2)) >> 25;
    const unsigned long long mb =
        (__ballot((lane >= 50) && (x != 0)) >> 50) |
        (__ballot((lane < 11) && (y != 0)) << 14);
    const int cpe_idx = mb ? __builtin_ctzll((long long)mb) : 25;
    const unsigned long long og2 = spread25(og_lo) | (spread25(og_hi) << 1);

    // scores: wave-uniform float4 loads (scalar-promotable), head = g4
    const int sb = __builtin_amdgcn_readfirstlane(cpe_idx * 400);
    float sc[25];
#pragma unroll
    for (int ij = 0; ij < 25; ++ij) {
      const int ig = (int)((ig_lo >> ij) & 1ull) | ((int)((ig_hi >> ij) & 1ull) << 1);
      const float4 s4 = *(const float4*)(stab + sb + ig * 100 + ij * 4);
      sc[ij] = (g4 < 2) ? (g4 == 0 ? s4.x : s4.y) : (g4 == 2 ? s4.z : s4.w);
    }
    // tree max (4 partial chains, depth ~8 instead of 25)
    float m0 = sc[0], m1 = sc[1], m2 = sc[2], m3 = sc[3];
#pragma unroll
    for (int ij = 4; ij < 24; ij += 4) {
      m0 = fmaxf(m0, sc[ij]);
      m1 = fmaxf(m1, sc[ij + 1]);
      m2 = fmaxf(m2, sc[ij + 2]);
      m3 = fmaxf(m3, sc[ij + 3]);
    }
    const float mx = fmaxf(fmaxf(fmaxf(m0, m1), fmaxf(m2, m3)), sc[24]);
    // exp + tree sum
    float s0 = 0.f, s1 = 0.f, s2 = 0.f, s3 = 0.f;
#pragma unroll
    for (int ij = 0; ij < 24; ij += 4) {
      sc[ij]     = __expf(sc[ij] - mx);     s0 += sc[ij];
      sc[ij + 1] = __expf(sc[ij + 1] - mx); s1 += sc[ij + 1];
      sc[ij + 2] = __expf(sc[ij + 2] - mx); s2 += sc[ij + 2];
      sc[ij + 3] = __expf(sc[ij + 3] - mx); s3 += sc[ij + 3];
    }
    sc[24] = __expf(sc[24] - mx);
    const float inv = 1.0f / (((s0 + s1) + (s2 + s3)) + sc[24]);

    // attended: 4 partial FMA chains
    float r0 = 0.f, r1 = 0.f, r2 = 0.f, r3 = 0.f;
#pragma unroll
    for (int ij = 0; ij < 24; ij += 4) {
      const int ia = (int)((ig_lo >> ij) & 1ull) | ((int)((ig_hi >> ij) & 1ull) << 1);
      const int ib2 = (int)((ig_lo >> (ij+1)) & 1ull) | ((int)((ig_hi >> (ij+1)) & 1ull) << 1);
      const int ic = (int)((ig_lo >> (ij+2)) & 1ull) | ((int)((ig_hi >> (ij+2)) & 1ull) << 1);
      const int id = (int)((ig_lo >> (ij+3)) & 1ull) | ((int)((ig_hi >> (ij+3)) & 1ull) << 1);
      r0 = fmaf(sc[ij],     vtab[(ia * 25 + ij) * 64 + lane], r0);
      r1 = fmaf(sc[ij + 1], vtab[(ib2 * 25 + ij + 1) * 64 + lane], r1);
      r2 = fmaf(sc[ij + 2], vtab[(ic * 25 + ij + 2) * 64 + lane], r2);
      r3 = fmaf(sc[ij + 3], vtab[(id * 25 + ij + 3) * 64 + lane], r3);
    }
    {
      const int ig24 = (int)((ig_lo >> 24) & 1ull) | ((int)((ig_hi >> 24) & 1ull) << 1);
      r0 = fmaf(sc[24], vtab[(ig24 * 25 + 24) * 64 + lane], r0);
    }
    const float ra = ((r0 + r1) + (r2 + r3)) * inv;
    const unsigned short hi = f2bf(ra);
    const int raoff = (r * 128 + lane * 2) ^ ((r & 7) << 4);
    *(short*)((char*)lds_raH + raoff) = (short)hi;
    *(short*)((char*)lds_raL + raoff) = (short)f2bf(ra - bf2f(hi));

    // pre = bias1 + cpeproj[cpe] + pair-table sums + cell24 (2 partial chains)
    float2 aA = ((const float2*)bias1)[lane];
    float2 aB = ((const float2*)cpeproj)[cpe_idx * 64 + lane];
#pragma unroll
    for (int p = 0; p < 12; p += 2) {
      const int og4a = (int)((og2 >> (4 * p)) & 15ull);
      const int og4b = (int)((og2 >> (4 * p + 4)) & 15ull);
      const float2 va = ((const float2*)outproj2)[(p * 16 + og4a) * 64 + lane];
      const float2 vb = ((const float2*)outproj2)[((p + 1) * 16 + og4b) * 64 + lane];
      aA.x += va.x; aA.y += va.y;
      aB.x += vb.x; aB.y += vb.y;
    }
    {
      const int og24 = (int)((og2 >> 48) & 3ull);
      const float2 v = ((const float2*)outproj)[(og24 * 25 + 24) * 64 + lane];
      aA.x += v.x; aA.y += v.y;
    }
    *(float2*)&lds_pre[r][2 * lane] = make_float2(aA.x + aB.x, aA.y + aB.y);
  }
  __syncthreads();

  // ---------------- phase B: MFMA dense layers ----------------
  // Wave wv owns column-tiles nt = wv*2, wv*2+1. B-frags direct from global.
  const int rswz = (row16 & 7) << 4;
  const short8v aH0 = *(const short8v*)((char*)lds_raH + ((row16 * 128 + g4 * 16) ^ rswz));
  const short8v aH1 = *(const short8v*)((char*)lds_raH + ((row16 * 128 + 64 + g4 * 16) ^ rswz));
  const short8v aL0 = *(const short8v*)((char*)lds_raL + ((row16 * 128 + g4 * 16) ^ rswz));
  const short8v aL1 = *(const short8v*)((char*)lds_raL + ((row16 * 128 + 64 + g4 * 16) ^ rswz));

  float4v acc[2];
  short8v bw[2][2];
#pragma unroll
  for (int t = 0; t < 2; ++t) {
    const int nt = wv * 2 + t;
#pragma unroll
    for (int ks = 0; ks < 2; ++ks)
      bw[t][ks] = *(const short8v*)(wovT + (nt * 16 + row16) * 64 + ks * 32 + g4 * 8);
    // C-init from pre (C/D layout: col = lane&15, row = (lane>>4)*4 + reg)
#pragma unroll
    for (int rr = 0; rr < 4; ++rr)
      acc[t][rr] = lds_pre[g4 * 4 + rr][nt * 16 + row16];
  }
#pragma unroll
  for (int t = 0; t < 2; ++t) {
    acc[t] = __builtin_amdgcn_mfma_f32_16x16x32_bf16(aL0, bw[t][0], acc[t], 0, 0, 0);
    acc[t] = __builtin_amdgcn_mfma_f32_16x16x32_bf16(aL1, bw[t][1], acc[t], 0, 0, 0);
    acc[t] = __builtin_amdgcn_mfma_f32_16x16x32_bf16(aH0, bw[t][0], acc[t], 0, 0, 0);
    acc[t] = __builtin_amdgcn_mfma_f32_16x16x32_bf16(aH1, bw[t][1], acc[t], 0, 0, 0);
  }

  // relu -> hidden bf16 hi+lo into swizzled LDS
#pragma unroll
  for (int t = 0; t < 2; ++t) {
    const int col = (wv * 2 + t) * 16 + row16;
#pragma unroll
    for (int rr = 0; rr < 4; ++rr) {
      const int row = g4 * 4 + rr;
      const float hv = fmaxf(acc[t][rr], 0.f);
      const unsigned short hb = f2bf(hv);
      const int off = (row * 256 + col * 2) ^ ((row & 7) << 4);
      *(short*)((char*)lds_hidH + off) = (short)hb;
      *(short*)((char*)lds_hidL + off) = (short)f2bf(hv - bf2f(hb));
    }
  }
  __syncthreads();

  // out = hidden @ cb_w2 + b2 (B-frags direct from cbw2T global, L1-hot)
  short8v ahH[4], ahL[4];
#pragma unroll
  for (int ks = 0; ks < 4; ++ks) {
    const int off = (row16 * 256 + ks * 64 + g4 * 16) ^ rswz;
    ahH[ks] = *(const short8v*)((char*)lds_hidH + off);
    ahL[ks] = *(const short8v*)((char*)lds_hidL + off);
  }
#pragma unroll
  for (int t = 0; t < 2; ++t) {
    const int col = (wv * 2 + t) * 16 + row16;
    float4v c2 = {0.f, 0.f, 0.f, 0.f};
#pragma unroll
    for (int ks = 0; ks < 4; ++ks) {
      const short8v bb = *(const short8v*)(cbw2T + col * 128 + ks * 32 + g4 * 8);
      c2 = __builtin_amdgcn_mfma_f32_16x16x32_bf16(ahL[ks], bb, c2, 0, 0, 0);
      c2 = __builtin_amdgcn_mfma_f32_16x16x32_bf16(ahH[ks], bb, c2, 0, 0, 0);
    }
    const float bv = cb_b2[col];
#pragma unroll
    for (int rr = 0; rr < 4; ++rr)
      out[(bbase + g4 * 4 + rr) * 128 + col] = c2[rr] + bv;
  }
}

extern "C" void kernel_launch(void* const* d_in, const int* in_sizes, int n_in,
                              void* d_out, int out_size, void* d_ws, size_t ws_size,
                              hipStream_t stream) {
  const int*   obs         = (const int*)d_in[0];
  const float* color_embed = (const float*)d_in[1];
  const float* row_embed   = (const float*)d_in[2];
  const float* col_embed   = (const float*)d_in[3];
  const float* ip_w1 = (const float*)d_in[4];
  const float* ip_b1 = (const float*)d_in[5];
  const float* ip_w2 = (const float*)d_in[6];
  const float* ip_b2 = (const float*)d_in[7];
  const float* q_w = (const float*)d_in[8];
  const float* q_b = (const float*)d_in[9];
  const float* k_w = (const float*)d_in[10];
  const float* k_b = (const float*)d_in[11];
  const float* v_w = (const float*)d_in[12];
  const float* v_b = (const float*)d_in[13];
  const float* o_w = (const float*)d_in[14];
  const float* o_b = (const float*)d_in[15];
  const float* op_w1 = (const float*)d_in[16];
  const float* op_b1 = (const float*)d_in[17];
  const float* op_w2 = (const float*)d_in[18];
  const float* op_b2 = (const float*)d_in[19];
  const float* cb_w1 = (const float*)d_in[20];
  const float* cb_b1 = (const float*)d_in[21];
  const float* cb_w2 = (const float*)d_in[22];
  const float* cb_b2 = (const float*)d_in[23];

  float* ws = (float*)d_ws;
  float* qtab    = ws;                 // 1664
  float* cpeproj = qtab + 1664;        // 3328
  float* ktab    = cpeproj + 3328;     // 6400
  float* vtab    = ktab + 6400;        // 6400
  float* outproj = vtab + 6400;        // 12800
  float* wov     = outproj + 12800;    // 8192
  float* bias1   = wov + 8192;         // 128
  float* stab    = bias1 + 128;        // 10400
  unsigned short* wovT  = (unsigned short*)(stab + 10400);        // 8192 shorts
  unsigned short* cbw2T = (unsigned short*)((float*)d_ws + 53408); // 16384 shorts
  float* outproj2 = (float*)d_ws + 61600;  // 24576
  float* inpval   = (float*)d_ws + 86176;  // 6400
  float* outval   = inpval + 6400;         // 6400
  // total 98976 floats ≈ 396 KB of d_ws

  prep12<<<200, 128, 0, stream>>>(color_embed, row_embed, col_embed,
                                  ip_w1, ip_b1, ip_w2, ip_b2,
                                  op_w1, op_b1, op_w2, op_b2, inpval, outval);
  prep3<<<152, 256, 0, stream>>>(row_embed, col_embed, k_w, k_b, v_w, v_b,
                                 q_w, q_b, o_w, o_b, cb_w1, cb_b1,
                                 inpval, outval,
                                 ktab, vtab, outproj, qtab, cpeproj, wov, bias1);
  prepC<<<233, 256, 0, stream>>>(qtab, ktab, wov, cb_w2, outproj,
                                 stab, wovT, cbw2T, outproj2);
  arc_fused<<<2048, 256, 0, stream>>>(obs, stab, vtab, outproj, outproj2,
                                      cpeproj, bias1, wovT, cbw2T, cb_b2,
                                      (float*)d_out);
}

// Round 7
// 48.278 us; speedup vs baseline: 1.8261x; 1.4397x over previous
//
#include <hip/hip_runtime.h>

// PositionAwareARCEncoder fused kernels.
// B=32768, H=W=5, NC=4, E=64, HID=128, OUT=128, NH=4, HD=16.
//
// R6: phase A is GEMM-ified. Per block (16 batches, 4 waves):
//  - decode: ballots per batch (4 iters/wave), masks selected per lane-group
//  - softmax: thread-per-(batch,head,jj): ~7 scores each, quad shfl reduce
//  - p scattered as bf16 one-hot-weighted LDS matrix W[h][16][128] (k=ig*25+ij)
//  - OG[16][160] one-hot: og cells (k=og*25+ij), cpe one-hot hi/lo, bias-one
//  - ra  = W_h @ vtabT_h        (MFMA, wave=head)
//  - pre = OG @ outprojBT       (MFMA; outproj single bf16, cpe/bias hi+lo)
//  - hidden = relu(pre + ra@wov) ; out = hidden@cb_w2 + b2  (MFMA, hi/lo)
// Tables in d_ws (~355 KB), built by prep12/prep3 (unchanged, proven) + prepC.

typedef __attribute__((ext_vector_type(8))) short short8v;
typedef __attribute__((ext_vector_type(4))) float float4v;

static __device__ __forceinline__ unsigned short f2bf(float f) {
  unsigned int u = __float_as_uint(f);
  unsigned int r = (u + 0x7fffu + ((u >> 16) & 1u)) >> 16;
  return (unsigned short)r;
}
static __device__ __forceinline__ float bf2f(unsigned short s) {
  return __uint_as_float(((unsigned int)s) << 16);
}

__global__ void prep12(const float* __restrict__ color_embed,
                       const float* __restrict__ row_embed,
                       const float* __restrict__ col_embed,
                       const float* __restrict__ ip_w1, const float* __restrict__ ip_b1,
                       const float* __restrict__ ip_w2, const float* __restrict__ ip_b2,
                       const float* __restrict__ op_w1, const float* __restrict__ op_b1,
                       const float* __restrict__ op_w2, const float* __restrict__ op_b2,
                       float* __restrict__ inpval, float* __restrict__ outval) {
  __shared__ float feat[128];
  __shared__ float h1[128];
  const int bid = blockIdx.x;       // 0..199
  const int path = bid / 100;
  const int cij = bid % 100;
  const int c = cij / 25, ij = cij % 25, gi = ij / 5, gj = ij % 5;
  const int t = threadIdx.x;        // 128 threads
  if (t < 64)      feat[t] = color_embed[c * 64 + t];
  else if (t < 96) feat[t] = row_embed[gi * 32 + (t - 64)];
  else             feat[t] = col_embed[gj * 32 + (t - 96)];
  __syncthreads();
  const float* w1 = path ? op_w1 : ip_w1;
  const float* b1 = path ? op_b1 : ip_b1;
  float acc = b1[t];
#pragma unroll 8
  for (int d = 0; d < 128; ++d) acc = fmaf(feat[d], w1[d * 128 + t], acc);
  h1[t] = fmaxf(acc, 0.f);
  __syncthreads();
  if (t < 64) {
    const float* w2 = path ? op_w2 : ip_w2;
    const float* b2 = path ? op_b2 : ip_b2;
    float v = b2[t];
#pragma unroll 8
    for (int d = 0; d < 128; ++d) v = fmaf(h1[d], w2[d * 64 + t], v);
    (path ? outval : inpval)[cij * 64 + t] = v;
  }
}

__global__ void prep3(const float* __restrict__ row_embed, const float* __restrict__ col_embed,
                      const float* __restrict__ k_w, const float* __restrict__ k_b,
                      const float* __restrict__ v_w, const float* __restrict__ v_b,
                      const float* __restrict__ q_w, const float* __restrict__ q_b,
                      const float* __restrict__ o_w, const float* __restrict__ o_b,
                      const float* __restrict__ cb_w1, const float* __restrict__ cb_b1,
                      const float* __restrict__ inpval, const float* __restrict__ outval,
                      float* __restrict__ ktab, float* __restrict__ vtab,
                      float* __restrict__ outproj, float* __restrict__ qtab,
                      float* __restrict__ cpeproj, float* __restrict__ wov,
                      float* __restrict__ bias1) {
  const int tid = blockIdx.x * 256 + threadIdx.x;
  if (tid < 6400) {                       // ktab[100][64]
    const int cij = tid >> 6, e2 = tid & 63;
    const float* x = inpval + cij * 64;
    float a = k_b[e2];
#pragma unroll 8
    for (int e = 0; e < 64; ++e) a = fmaf(x[e], k_w[e * 64 + e2], a);
    ktab[tid] = a;
  } else if (tid < 12800) {               // vtab[100][64]
    const int l = tid - 6400;
    const int cij = l >> 6, e2 = l & 63;
    const float* x = inpval + cij * 64;
    float a = v_b[e2];
#pragma unroll 8
    for (int e = 0; e < 64; ++e) a = fmaf(x[e], v_w[e * 64 + e2], a);
    vtab[l] = a;
  } else if (tid < 25600) {               // outproj[100][128] (1/25 folded)
    const int l = tid - 12800;
    const int cij = l >> 7, jj = l & 127;
    const float* x = outval + cij * 64;
    float a = 0.f;
#pragma unroll 8
    for (int e = 0; e < 64; ++e) a = fmaf(x[e], cb_w1[(64 + e) * 128 + jj], a);
    outproj[l] = a * (1.f / 25.f);
  } else if (tid < 27264) {               // qtab[26][64]
    const int l = tid - 25600;
    const int p = l >> 6, e2 = l & 63;
    float a = q_b[e2];
    if (p < 25) {
      const int r = p / 5, c = p % 5;
#pragma unroll 8
      for (int e = 0; e < 32; ++e) a = fmaf(row_embed[r * 32 + e], q_w[e * 64 + e2], a);
#pragma unroll 8
      for (int e = 0; e < 32; ++e) a = fmaf(col_embed[c * 32 + e], q_w[(32 + e) * 64 + e2], a);
    }
    qtab[l] = a;
  } else if (tid < 30592) {               // cpeproj[26][128]
    const int l = tid - 27264;
    const int p = l >> 7, jj = l & 127;
    float a = 0.f;
    if (p < 25) {
      const int r = p / 5, c = p % 5;
#pragma unroll 8
      for (int e = 0; e < 32; ++e) a = fmaf(row_embed[r * 32 + e], cb_w1[(128 + e) * 128 + jj], a);
#pragma unroll 8
      for (int e = 0; e < 32; ++e) a = fmaf(col_embed[c * 32 + e], cb_w1[(160 + e) * 128 + jj], a);
    }
    cpeproj[l] = a;
  } else if (tid < 38784) {               // wov[64][128]
    const int l = tid - 30592;
    const int d = l >> 7, jj = l & 127;
    float a = 0.f;
#pragma unroll 8
    for (int e = 0; e < 64; ++e) a = fmaf(o_w[d * 64 + e], cb_w1[e * 128 + jj], a);
    wov[l] = a;
  } else if (tid < 38912) {               // bias1[128]
    const int jj = tid - 38784;
    float a = cb_b1[jj];
#pragma unroll 8
    for (int e = 0; e < 64; ++e) a = fmaf(o_b[e], cb_w1[e * 128 + jj], a);
    bias1[jj] = a;
  }
}

// stab + bf16 B-matrices (after prep3)
__global__ void prepC(const float* __restrict__ qtab, const float* __restrict__ ktab,
                      const float* __restrict__ wov, const float* __restrict__ cb_w2,
                      const float* __restrict__ outproj, const float* __restrict__ vtab,
                      const float* __restrict__ cpeproj, const float* __restrict__ bias1,
                      float* __restrict__ stab, unsigned short* __restrict__ wovT,
                      unsigned short* __restrict__ cbw2T,
                      unsigned short* __restrict__ vtabT,
                      unsigned short* __restrict__ outprojBT) {
  const int tid = blockIdx.x * 256 + threadIdx.x;
  if (tid < 10400) {                         // stab[cpe][ig][ij][h]
    const int h = tid & 3;
    const int ij = (tid >> 2) % 25;
    const int ig = ((tid >> 2) / 25) & 3;
    const int cpe = (tid >> 2) / 100;
    const float* qq = qtab + cpe * 64 + h * 16;
    const float* kk = ktab + (ig * 25 + ij) * 64 + h * 16;
    float a = 0.f;
#pragma unroll
    for (int d = 0; d < 16; ++d) a = fmaf(qq[d], kk[d], a);
    stab[tid] = a * 0.25f;
  } else if (tid < 18592) {                  // wovT[col 128][k 64]
    const int i = tid - 10400;
    const int j = i >> 6, d = i & 63;
    wovT[i] = f2bf(wov[d * 128 + j]);
  } else if (tid < 34976) {                  // cbw2T[col 128][k 128]
    const int i = tid - 18592;
    const int j = i >> 7, k = i & 127;
    cbw2T[i] = f2bf(cb_w2[k * 128 + j]);
  } else if (tid < 43168) {                  // vtabT[h 4][d 16][k 128]
    const int i = tid - 34976;
    const int h = i >> 11, rest = i & 2047;
    const int d = rest >> 7, k = rest & 127;
    vtabT[i] = (k < 100) ? f2bf(vtab[k * 64 + h * 16 + d]) : 0;
  } else if (tid < 63648) {                  // outprojBT[col 128][k 160]
    const int i = tid - 43168;
    const int col = i / 160, k = i % 160;
    unsigned short v = 0;
    if (k < 100) {
      v = f2bf(outproj[k * 128 + col]);
    } else if (k < 126) {
      v = f2bf(cpeproj[(k - 100) * 128 + col]);
    } else if (k == 126) {
      v = f2bf(bias1[col]);
    } else if (k < 153) {
      const float x = cpeproj[(k - 127) * 128 + col];
      v = f2bf(x - bf2f(f2bf(x)));
    } else if (k == 153) {
      const float x = bias1[col];
      v = f2bf(x - bf2f(f2bf(x)));
    }
    outprojBT[i] = v;
  }
}

__global__ __launch_bounds__(256) void arc_fused(
    const int* __restrict__ obs,
    const float* __restrict__ stab,
    const unsigned short* __restrict__ vtabT,
    const unsigned short* __restrict__ outprojBT,
    const unsigned short* __restrict__ wovT,
    const unsigned short* __restrict__ cbw2T,
    const float* __restrict__ cb_b2,
    float* __restrict__ out) {
  __shared__ __align__(16) short lds_w[4 * 16 * 128];   // 16 KB  W[h][b][128], swz
  __shared__ __align__(16) short lds_og[16 * 256];      // 8 KB   OG[b][256] (160 used), swz
  __shared__ __align__(16) short lds_raH[1024];         // [16][64]
  __shared__ __align__(16) short lds_raL[1024];
  __shared__ __align__(16) short lds_hidH[2048];        // [16][128]
  __shared__ __align__(16) short lds_hidL[2048];
  // total 36 KB -> 4 blocks/CU

  const int tid = threadIdx.x;
  const int lane = tid & 63, wv = tid >> 6;
  const int row16 = lane & 15, g4 = lane >> 4;
  const int bbase = blockIdx.x * 16;

  // ---- zero W / OG ----
  {
    const int4 z = {0, 0, 0, 0};
    int4* pw = (int4*)lds_w;
    int4* pg = (int4*)lds_og;
#pragma unroll
    for (int i = 0; i < 4; ++i) pw[tid + 256 * i] = z;
#pragma unroll
    for (int i = 0; i < 2; ++i) pg[tid + 256 * i] = z;
  }
  __syncthreads();

  // ---- decode: 4 batches per wave; select this lane-group's masks ----
  unsigned iglo = 0, ighi = 0, oglo = 0, oghi = 0;
  int cpe_sel = 0;
  const int b_loc = wv * 4 + g4;   // this lane's batch row (0..15)
#pragma unroll
  for (int e = 0; e < 4; ++e) {
    const int* ob = obs + (bbase + wv * 4 + e) * 75;
    const int x = ob[lane];
    const int y = (lane < 11) ? ob[64 + lane] : 0;
    const unsigned long long blo = __ballot(x & 1);
    const unsigned long long bhi = __ballot(x & 2);
    const unsigned long long bnzy = __ballot((lane < 11) && (y != 0));
    const unsigned e_iglo = (unsigned)(blo & 0x1FFFFFFull);
    const unsigned e_ighi = (unsigned)(bhi & 0x1FFFFFFull);
    const unsigned e_oglo = (unsigned)((blo >> 25) & 0x1FFFFFFull);
    const unsigned e_oghi = (unsigned)((bhi >> 25) & 0x1FFFFFFull);
    const unsigned e_mb = (unsigned)(((blo | bhi) >> 50) | (bnzy << 14));
    const int e_cpe = e_mb ? __builtin_ctz(e_mb) : 25;
    if (g4 == e) { iglo = e_iglo; ighi = e_ighi; oglo = e_oglo; oghi = e_oghi; cpe_sel = e_cpe; }
  }

  // ---- scores + softmax: thread-per-(batch, head hh, lane-slot jj) ----
  const int hh = row16 >> 2, jj = row16 & 3;
  float sv[7], ev[7];
  int cij7[7];
  float mx = -1e30f;
  const float* sb = stab + cpe_sel * 400 + hh;
#pragma unroll
  for (int m = 0; m < 7; ++m) {
    const int ij = jj + 4 * m;
    if (ij < 25) {
      const int ig = ((iglo >> ij) & 1) | (((ighi >> ij) & 1) << 1);
      cij7[m] = ig * 25 + ij;
      sv[m] = sb[ig * 100 + ij * 4];
      mx = fmaxf(mx, sv[m]);
    }
  }
  mx = fmaxf(mx, __shfl_xor(mx, 1));
  mx = fmaxf(mx, __shfl_xor(mx, 2));
  float sum = 0.f;
#pragma unroll
  for (int m = 0; m < 7; ++m) {
    const int ij = jj + 4 * m;
    if (ij < 25) { ev[m] = __expf(sv[m] - mx); sum += ev[m]; }
  }
  sum += __shfl_xor(sum, 1);
  sum += __shfl_xor(sum, 2);
  const float inv = __builtin_amdgcn_rcpf(sum);
  const int bswz = (b_loc & 7) << 4;
#pragma unroll
  for (int m = 0; m < 7; ++m) {
    const int ij = jj + 4 * m;
    if (ij < 25) {
      const unsigned short pb = f2bf(ev[m] * inv);
      const int woff = (hh * 4096 + b_loc * 256 + cij7[m] * 2) ^ bswz;
      *(short*)((char*)lds_w + woff) = (short)pb;
      const int og = ((oglo >> ij) & 1) | (((oghi >> ij) & 1) << 1);
      const int ooff = (b_loc * 512 + (og * 25 + ij) * 2) ^ bswz;
      *(short*)((char*)lds_og + ooff) = (short)0x3F80;   // 1.0 bf16
    }
  }
  if (row16 == 15) {   // one thread per batch: cpe one-hot (hi+lo rows) + bias-one
    *(short*)((char*)lds_og + ((b_loc * 512 + (100 + cpe_sel) * 2) ^ bswz)) = (short)0x3F80;
    *(short*)((char*)lds_og + ((b_loc * 512 + (127 + cpe_sel) * 2) ^ bswz)) = (short)0x3F80;
    *(short*)((char*)lds_og + ((b_loc * 512 + 126 * 2) ^ bswz)) = (short)0x3F80;
    *(short*)((char*)lds_og + ((b_loc * 512 + 153 * 2) ^ bswz)) = (short)0x3F80;
  }
  __syncthreads();

  // ---- phase B ----
  const int rsw = (row16 & 7) << 4;

  // ra-GEMM: wave wv = head wv; out cols = dims of head wv
  float4v rc = {0.f, 0.f, 0.f, 0.f};
#pragma unroll
  for (int ks = 0; ks < 4; ++ks) {
    const short8v a = *(const short8v*)((char*)lds_w +
        ((wv * 4096 + row16 * 256 + ks * 64 + g4 * 16) ^ rsw));
    const short8v bf = *(const short8v*)(vtabT + wv * 2048 + row16 * 128 + ks * 32 + g4 * 8);
    rc = __builtin_amdgcn_mfma_f32_16x16x32_bf16(a, bf, rc, 0, 0, 0);
  }
  // rc[r] = ra[b = g4*4+r][dim = wv*16+row16] -> hi/lo LDS
#pragma unroll
  for (int r = 0; r < 4; ++r) {
    const int b = g4 * 4 + r;
    const float hv = rc[r];
    const unsigned short hb = f2bf(hv);
    const int off = (b * 128 + (wv * 16 + row16) * 2) ^ ((b & 7) << 4);
    *(short*)((char*)lds_raH + off) = (short)hb;
    *(short*)((char*)lds_raL + off) = (short)f2bf(hv - bf2f(hb));
  }

  // pre-GEMM: OG[16][160] @ outprojBT -> acc (2 col-tiles per wave)
  float4v acc[2];
  acc[0] = (float4v){0.f, 0.f, 0.f, 0.f};
  acc[1] = (float4v){0.f, 0.f, 0.f, 0.f};
  const int c0 = (wv * 2) * 16 + row16, c1 = (wv * 2 + 1) * 16 + row16;
#pragma unroll
  for (int ks = 0; ks < 5; ++ks) {
    const short8v a = *(const short8v*)((char*)lds_og +
        ((row16 * 512 + ks * 64 + g4 * 16) ^ rsw));
    const short8v b0 = *(const short8v*)(outprojBT + c0 * 160 + ks * 32 + g4 * 8);
    const short8v b1 = *(const short8v*)(outprojBT + c1 * 160 + ks * 32 + g4 * 8);
    acc[0] = __builtin_amdgcn_mfma_f32_16x16x32_bf16(a, b0, acc[0], 0, 0, 0);
    acc[1] = __builtin_amdgcn_mfma_f32_16x16x32_bf16(a, b1, acc[1], 0, 0, 0);
  }
  __syncthreads();   // lds_ra ready

  // wov-GEMM: acc += ra @ wov (hi/lo compensated)
  const short8v aH0 = *(const short8v*)((char*)lds_raH + ((row16 * 128 + g4 * 16) ^ rsw));
  const short8v aH1 = *(const short8v*)((char*)lds_raH + ((row16 * 128 + 64 + g4 * 16) ^ rsw));
  const short8v aL0 = *(const short8v*)((char*)lds_raL + ((row16 * 128 + g4 * 16) ^ rsw));
  const short8v aL1 = *(const short8v*)((char*)lds_raL + ((row16 * 128 + 64 + g4 * 16) ^ rsw));
#pragma unroll
  for (int t = 0; t < 2; ++t) {
    const int nt = wv * 2 + t;
    const short8v bw0 = *(const short8v*)(wovT + (nt * 16 + row16) * 64 + g4 * 8);
    const short8v bw1 = *(const short8v*)(wovT + (nt * 16 + row16) * 64 + 32 + g4 * 8);
    acc[t] = __builtin_amdgcn_mfma_f32_16x16x32_bf16(aL0, bw0, acc[t], 0, 0, 0);
    acc[t] = __builtin_amdgcn_mfma_f32_16x16x32_bf16(aL1, bw1, acc[t], 0, 0, 0);
    acc[t] = __builtin_amdgcn_mfma_f32_16x16x32_bf16(aH0, bw0, acc[t], 0, 0, 0);
    acc[t] = __builtin_amdgcn_mfma_f32_16x16x32_bf16(aH1, bw1, acc[t], 0, 0, 0);
  }

  // relu -> hidden bf16 hi+lo into swizzled LDS
#pragma unroll
  for (int t = 0; t < 2; ++t) {
    const int col = (wv * 2 + t) * 16 + row16;
#pragma unroll
    for (int rr = 0; rr < 4; ++rr) {
      const int row = g4 * 4 + rr;
      const float hv = fmaxf(acc[t][rr], 0.f);
      const unsigned short hb = f2bf(hv);
      const int off = (row * 256 + col * 2) ^ ((row & 7) << 4);
      *(short*)((char*)lds_hidH + off) = (short)hb;
      *(short*)((char*)lds_hidL + off) = (short)f2bf(hv - bf2f(hb));
    }
  }
  __syncthreads();

  // out = hidden @ cb_w2 + b2
  short8v ahH[4], ahL[4];
#pragma unroll
  for (int ks = 0; ks < 4; ++ks) {
    const int off = (row16 * 256 + ks * 64 + g4 * 16) ^ rsw;
    ahH[ks] = *(const short8v*)((char*)lds_hidH + off);
    ahL[ks] = *(const short8v*)((char*)lds_hidL + off);
  }
#pragma unroll
  for (int t = 0; t < 2; ++t) {
    const int col = (wv * 2 + t) * 16 + row16;
    float4v c2 = {0.f, 0.f, 0.f, 0.f};
#pragma unroll
    for (int ks = 0; ks < 4; ++ks) {
      const short8v bb = *(const short8v*)(cbw2T + col * 128 + ks * 32 + g4 * 8);
      c2 = __builtin_amdgcn_mfma_f32_16x16x32_bf16(ahL[ks], bb, c2, 0, 0, 0);
      c2 = __builtin_amdgcn_mfma_f32_16x16x32_bf16(ahH[ks], bb, c2, 0, 0, 0);
    }
    const float bv = cb_b2[col];
#pragma unroll
    for (int rr = 0; rr < 4; ++rr)
      out[(bbase + g4 * 4 + rr) * 128 + col] = c2[rr] + bv;
  }
}

extern "C" void kernel_launch(void* const* d_in, const int* in_sizes, int n_in,
                              void* d_out, int out_size, void* d_ws, size_t ws_size,
                              hipStream_t stream) {
  const int*   obs         = (const int*)d_in[0];
  const float* color_embed = (const float*)d_in[1];
  const float* row_embed   = (const float*)d_in[2];
  const float* col_embed   = (const float*)d_in[3];
  const float* ip_w1 = (const float*)d_in[4];
  const float* ip_b1 = (const float*)d_in[5];
  const float* ip_w2 = (const float*)d_in[6];
  const float* ip_b2 = (const float*)d_in[7];
  const float* q_w = (const float*)d_in[8];
  const float* q_b = (const float*)d_in[9];
  const float* k_w = (const float*)d_in[10];
  const float* k_b = (const float*)d_in[11];
  const float* v_w = (const float*)d_in[12];
  const float* v_b = (const float*)d_in[13];
  const float* o_w = (const float*)d_in[14];
  const float* o_b = (const float*)d_in[15];
  const float* op_w1 = (const float*)d_in[16];
  const float* op_b1 = (const float*)d_in[17];
  const float* op_w2 = (const float*)d_in[18];
  const float* op_b2 = (const float*)d_in[19];
  const float* cb_w1 = (const float*)d_in[20];
  const float* cb_b1 = (const float*)d_in[21];
  const float* cb_w2 = (const float*)d_in[22];
  const float* cb_b2 = (const float*)d_in[23];

  float* ws = (float*)d_ws;
  float* qtab    = ws;                 // 1664
  float* cpeproj = qtab + 1664;        // 3328
  float* ktab    = cpeproj + 3328;     // 6400
  float* vtab    = ktab + 6400;        // 6400
  float* outproj = vtab + 6400;        // 12800
  float* wov     = outproj + 12800;    // 8192
  float* bias1   = wov + 8192;         // 128
  float* stab    = bias1 + 128;        // 10400  (ends at 49312)
  unsigned short* wovT      = (unsigned short*)(ws + 49312);  //  8192 us (4096 f)
  unsigned short* cbw2T     = (unsigned short*)(ws + 53408);  // 16384 us (8192 f)
  unsigned short* vtabT     = (unsigned short*)(ws + 61600);  //  8192 us (4096 f)
  unsigned short* outprojBT = (unsigned short*)(ws + 65696);  // 20480 us (10240 f)
  float* inpval  = ws + 75936;         // 6400
  float* outval  = inpval + 6400;      // 6400
  // total 88736 floats ~= 355 KB of d_ws

  prep12<<<200, 128, 0, stream>>>(color_embed, row_embed, col_embed,
                                  ip_w1, ip_b1, ip_w2, ip_b2,
                                  op_w1, op_b1, op_w2, op_b2, inpval, outval);
  prep3<<<152, 256, 0, stream>>>(row_embed, col_embed, k_w, k_b, v_w, v_b,
                                 q_w, q_b, o_w, o_b, cb_w1, cb_b1,
                                 inpval, outval,
                                 ktab, vtab, outproj, qtab, cpeproj, wov, bias1);
  prepC<<<249, 256, 0, stream>>>(qtab, ktab, wov, cb_w2, outproj, vtab,
                                 cpeproj, bias1,
                                 stab, wovT, cbw2T, vtabT, outprojBT);
  arc_fused<<<2048, 256, 0, stream>>>(obs, stab, vtabT, outprojBT,
                                      wovT, cbw2T, cb_b2, (float*)d_out);
}